// Round 9
// baseline (776.405 us; speedup 1.0000x reference)
//
#include <hip/hip_runtime.h>
#include <hip/hip_cooperative_groups.h>
#include <hip/hip_fp16.h>

namespace cg = cooperative_groups;

#define IN_C 64
#define HID_C 64
#define OUT_C 32
#define S_NODES  512    // bucket width in nodes
#define S_CAP  12288    // staging capacity per bucket (mean 8192, sigma ~90)
#define CHUNK_E 4096    // edges per bin work-item (16 per thread, register-cached)
// Packing invariant: src fits in 17 bits (N <= 131072), dst-local in 9 bits.

typedef _Float16 f16_t;
typedef f16_t f16x2 __attribute__((ext_vector_type(2)));

// 2 f16 MACs, fp32 accumulate (v_dot2_f32_f16). Both operands as packed u32.
__device__ __forceinline__ float dot2(unsigned int a, unsigned int b, float c) {
#if __has_builtin(__builtin_amdgcn_fdot2)
    return __builtin_amdgcn_fdot2(*(f16x2*)&a, *(f16x2*)&b, c, false);
#else
    float2 af = __half22float2(*(__half2*)&a);
    float2 bf = __half22float2(*(__half2*)&b);
    return fmaf(af.x, bf.x, fmaf(af.y, bf.y, c));
#endif
}

// s0 += f16lo(p)*w ; s1 += f16hi(p)*w  -- v_fma_mix_f32 (cvt fused into FMA).
__device__ __forceinline__ void mix2(float& s0, float& s1, unsigned int p, float w) {
    asm("v_fma_mix_f32 %0, %2, %3, %0 op_sel:[0,0,0] op_sel_hi:[1,0,0]\n\t"
        "v_fma_mix_f32 %1, %2, %3, %1 op_sel:[1,0,0] op_sel_hi:[1,0,0]"
        : "+v"(s0), "+v"(s1)
        : "v"(p), "v"(w));
}

// Wave-level inclusive scan (64 lanes) via shfl_up; 6 steps, no barriers.
__device__ __forceinline__ int wave_iscan(int x, int lane) {
#pragma unroll
    for (int o = 1; o < 64; o <<= 1) {
        int y = __shfl_up(x, o);
        if (lane >= o) x += y;
    }
    return x;
}

// ===========================================================================
// Phase bodies as __device__ functions. smem = 5128-int union (20.5 KB).
// Each body ends with __syncthreads() so LDS can be reused by the next
// grid-stride iteration. Logic is identical to the round-8 kernels.
// ===========================================================================

// ----- bin: counting-sort one 4096-edge chunk into bucket staging ----------
__device__ __forceinline__ void dev_bin(int b, int* smem, const void* ei, int E,
                                        int* bcur, int NB, int* __restrict__ staging) {
    int* cnt = smem;          int* boff = smem + 256;
    int* lcur = smem + 512;   int* gbase = smem + 768;
    int* stg = smem + 1024;   // CHUNK_E ints
    int* ps64 = smem + 5120;
    int* wsum = smem + 5121;  // 4 wave partial sums
    int tid = threadIdx.x;
    int lane = tid & 63, wv = tid >> 6;
    if (tid == 0) *ps64 = 1;
    cnt[tid] = 0;
    __syncthreads();
    // int32 interp: odd ints are real node ids (nonzero w.h.p.);
    // int64 interp: odd ints are high dwords (always 0 for ids < 2^31).
    if (2 * tid + 1 < 2 * E && ((const int*)ei)[2 * tid + 1] != 0) *ps64 = 0;
    __syncthreads();
    int is64 = *ps64;
    int e0 = b * CHUNK_E;
    int e1 = min(E, e0 + CHUNK_E);
    const int* ei32 = (const int*)ei;
    int rbuf[16];   // packed record  src | ((dst&511)<<17)
    int bbuf[16];   // bucket id (dst>>9), -1 = invalid slot
    if (is64) {
#pragma unroll
        for (int k = 0; k < 16; k++) {
            int e = e0 + (k << 8) + tid;
            if (e < e1) {
                int src = ei32[2 * e];            // low dword of int64
                int dst = ei32[2 * (E + e)];
                rbuf[k] = src | ((dst & 511) << 17);
                int bk = dst >> 9;
                bbuf[k] = bk;
                atomicAdd(&cnt[bk], 1);
            } else bbuf[k] = -1;
        }
    } else {
#pragma unroll
        for (int k = 0; k < 16; k++) {
            int e = e0 + (k << 8) + tid;
            if (e < e1) {
                int src = ei32[e];
                int dst = ei32[E + e];
                rbuf[k] = src | ((dst & 511) << 17);
                int bk = dst >> 9;
                bbuf[k] = bk;
                atomicAdd(&cnt[bk], 1);
            } else bbuf[k] = -1;
        }
    }
    __syncthreads();
    // exclusive scan of cnt via wave-shfl
    int v = cnt[tid];
    int xx = wave_iscan(v, lane);
    if (lane == 63) wsum[wv] = xx;
    __syncthreads();
    int add = 0;
#pragma unroll
    for (int w = 0; w < 3; w++) add += (w < wv) ? wsum[w] : 0;
    int bo = xx + add - v;
    boff[tid] = bo;
    lcur[tid] = bo;
    __syncthreads();
    // counting-sort scatter from registers
#pragma unroll
    for (int k = 0; k < 16; k++) {
        if (bbuf[k] >= 0) {
            int p = atomicAdd(&lcur[bbuf[k]], 1);
            stg[p] = rbuf[k];
        }
    }
    __syncthreads();
    if (tid < NB && cnt[tid] > 0) gbase[tid] = atomicAdd(&bcur[tid], cnt[tid]);
    __syncthreads();
    int sw = tid >> 4, sl = tid & 15;  // 16 subwaves of 16 lanes
    for (int bk = sw; bk < NB; bk += 16) {
        int c = cnt[bk];
        if (c == 0) continue;
        int o = boff[bk], g = gbase[bk];
        size_t gb = (size_t)bk * S_CAP;
        for (int j = sl; j < c; j += 16) {
            if (g + j < S_CAP) staging[gb + g + j] = stg[o + j];  // clamp (never hits)
        }
    }
    __syncthreads();  // LDS reuse guard for next work item
}

// ----- gemm1: t32[r,:] = x[r,:] @ W1 fp32 unscaled, 64 rows/tile -----------
__device__ __forceinline__ void dev_gemm1(int bb, int* smem,
                                          const float* __restrict__ x,
                                          const float* __restrict__ W1,
                                          float* __restrict__ t32, int n) {
    uint4* sA = (uint4*)smem;  // 64 rows x 64 f16 = 8 KB
    int tid = threadIdx.x;
    int lane = tid & 63, wave = tid >> 6;
    unsigned int wu[32];
#pragma unroll
    for (int k = 0; k < 32; k++) {
        f16x2 p;
        p.x = (f16_t)W1[(2 * k) * 64 + lane];
        p.y = (f16_t)W1[(2 * k + 1) * 64 + lane];
        wu[k] = *(unsigned int*)&p;
    }
    int base = bb * 64;
    const float2* A2 = (const float2*)x;
    int lim = n * 32;
    for (int i = tid; i < 2048; i += 256) {
        int gi = base * 32 + i;
        float2 v = (gi < lim) ? A2[gi] : make_float2(0.f, 0.f);
        ((__half2*)sA)[i] = __floats2half2_rn(v.x, v.y);
    }
    __syncthreads();
    int r0 = base + wave * 16;
    int r1 = min(r0 + 16, n);
    for (int r = r0; r < r1; r++) {
        int rr = r - base;
        float a0 = 0.f, a1 = 0.f;
#pragma unroll
        for (int j = 0; j < 8; j++) {
            uint4 u = sA[rr * 8 + j];  // uniform addr -> LDS broadcast, b128
            a0 = dot2(u.x, wu[4 * j], a0);
            a1 = dot2(u.y, wu[4 * j + 1], a1);
            a0 = dot2(u.z, wu[4 * j + 2], a0);
            a1 = dot2(u.w, wu[4 * j + 3], a1);
        }
        t32[(size_t)r * 64 + lane] = a0 + a1;
    }
    __syncthreads();  // LDS reuse guard
}

// ----- wconv: W2 / Wlin -> f16 col-major (no LDS) --------------------------
__device__ __forceinline__ void dev_wconv(const float* __restrict__ W2,
                                          const float* __restrict__ Wlin,
                                          unsigned short* __restrict__ Wh2,
                                          unsigned short* __restrict__ Whl) {
    int tid = threadIdx.x;
    for (int i = tid; i < 4096; i += 256) {
        int r = i >> 6, c = i & 63;
        f16_t h2 = (f16_t)W2[r * 64 + c];
        Wh2[c * 64 + r] = *(unsigned short*)&h2;
    }
    for (int i = tid; i < 2048; i += 256) {
        int r = i >> 5, c = i & 31;
        f16_t h = (f16_t)Wlin[r * 32 + c];
        Whl[c * 64 + r] = *(unsigned short*)&h;
    }
}

// ----- place: one bucket -- scans, offs/dinv/rec, scale+convert ------------
__device__ __forceinline__ void dev_place(int b, int* smem,
                                          const int* __restrict__ staging,
                                          const int* __restrict__ bcur,
                                          int* __restrict__ offs,
                                          float* __restrict__ dinv,
                                          int* __restrict__ rec,
                                          const float* __restrict__ t32,
                                          unsigned short* __restrict__ t16,
                                          int N, int NB) {
    int* sdeg = smem;                 // 512
    int* curs = smem + 512;           // 512
    int* sb   = smem + 1024;          // 256
    float* sdinv = (float*)(smem + 1280);  // 512
    int* wsum = smem + 1792;          // 4
    int tid = threadIdx.x;
    int lane = tid & 63, wv = tid >> 6;
    int v = (tid < NB) ? min(bcur[tid], S_CAP) : 0;
    sdeg[tid] = 0;
    sdeg[tid + 256] = 0;
    // scan A: bucket counts -> sb (inclusive)
    int xx = wave_iscan(v, lane);
    if (lane == 63) wsum[wv] = xx;
    __syncthreads();
    int add = 0;
#pragma unroll
    for (int w = 0; w < 3; w++) add += (w < wv) ? wsum[w] : 0;
    sb[tid] = xx + add;
    __syncthreads();
    int cnt = min(bcur[b], S_CAP);
    int bbase = sb[b] - cnt;  // exclusive prefix for this bucket
    if (b == NB - 1 && tid == 0) offs[N] = sb[255];
    int base = b * S_NODES;
    int nn = min(S_NODES, N - base);
    size_t sbase = (size_t)b * S_CAP;
    for (int j = tid; j < cnt; j += 256) atomicAdd(&sdeg[staging[sbase + j] >> 17], 1);
    __syncthreads();
    int d0 = sdeg[2 * tid], d1 = sdeg[2 * tid + 1];
    int t = d0 + d1;
    // scan B: degrees (2 per thread) -> exclusive prefix
    int x2 = wave_iscan(t, lane);
    if (lane == 63) wsum[wv] = x2;
    __syncthreads();
    int add2 = 0;
#pragma unroll
    for (int w = 0; w < 3; w++) add2 += (w < wv) ? wsum[w] : 0;
    int pre = bbase + x2 + add2 - t;  // exclusive
    curs[2 * tid] = pre;
    curs[2 * tid + 1] = pre + d0;
    float dv0 = rsqrtf((float)(d0 + 1));
    float dv1 = rsqrtf((float)(d1 + 1));
    sdinv[2 * tid] = dv0;
    sdinv[2 * tid + 1] = dv1;
    if (2 * tid < nn) {
        offs[base + 2 * tid] = pre;
        dinv[base + 2 * tid] = dv0;
    }
    if (2 * tid + 1 < nn) {
        offs[base + 2 * tid + 1] = pre + d0;
        dinv[base + 2 * tid + 1] = dv1;
    }
    __syncthreads();
    for (int j = tid; j < cnt; j += 256) {
        int pk = staging[sbase + j];
        int p = atomicAdd(&curs[pk >> 17], 1);
        rec[p] = pk & 0x1FFFF;
    }
    // scale+convert this bucket's rows: t16[r,:] = f16(t32[r,:]*dinv[r])
    const float4* tin = (const float4*)t32 + (size_t)base * 16;  // 16 float4/row
    uint2* tout = (uint2*)t16 + (size_t)base * 16;               // 16 uint2/row
    int jmax = nn * 16;
    for (int j = tid; j < jmax; j += 256) {
        float4 vv = tin[j];
        float w = sdinv[j >> 4];
        __half2 h0 = __floats2half2_rn(vv.x * w, vv.y * w);
        __half2 h1 = __floats2half2_rn(vv.z * w, vv.w * w);
        tout[j] = make_uint2(*(unsigned int*)&h0, *(unsigned int*)&h1);
    }
    __syncthreads();  // LDS reuse guard
}

// ----- aggregate helpers ---------------------------------------------------
__device__ __forceinline__ void agg_consume(const uint4& v, float w, float s[8]) {
    mix2(s[0], s[1], v.x, w);
    mix2(s[2], s[3], v.y, w);
    mix2(s[4], s[5], v.z, w);
    mix2(s[6], s[7], v.w, w);
}

template <int NU, bool MASK>
__device__ __forceinline__ void agg_chunk(const uint4* __restrict__ t4,
                                          const int* __restrict__ rec,
                                          int beg, int node, int me, int i,
                                          int g, int gl, float s[8]) {
    int srcs[NU];
    float ws[NU];
    uint4 vs[NU];
#pragma unroll
    for (int u = 0; u < NU; u++) {
        int it = i + u * 8 + g;
        if (MASK) {
            // OOB rec reads (it>=me) land in the staging region that follows
            // rec in the workspace; value is masked by ws=0.
            srcs[u] = (it < me) ? rec[beg + it] : node;
            ws[u] = (it < me) ? 1.f : 0.f;
        } else {
            srcs[u] = rec[beg + it];
        }
    }
#pragma unroll
    for (int u = 0; u < NU; u++) vs[u] = t4[(size_t)srcs[u] * 8 + gl];
#pragma unroll
    for (int u = 0; u < NU; u++) agg_consume(vs[u], MASK ? ws[u] : 1.f, s);
}

// ----- aggregate: one node-quad q (node = 4q + wave) -----------------------
__device__ __forceinline__ void dev_agg(int q, const unsigned short* __restrict__ t,
                                        const int* __restrict__ offs,
                                        const int* __restrict__ rec,
                                        const float* __restrict__ dinv,
                                        const float* __restrict__ bias,
                                        unsigned short* __restrict__ acc, int n) {
    int wave = q * 4 + (threadIdx.x >> 6);
    int lane = threadIdx.x & 63;
    if (wave >= n) return;  // fn-local return; caller loop continues
    int g = lane >> 3;   // edge group 0..7
    int gl = lane & 7;   // 16B slot within the 128B row
    int beg = offs[wave], end = offs[wave + 1];
    int me = end - beg;  // edge count (self handled separately)
    const uint4* t4 = (const uint4*)t;
    uint4 selfv;
    if (g == 0) selfv = t4[(size_t)wave * 8 + gl];  // exec-masked early load
    float s[8] = {0.f, 0.f, 0.f, 0.f, 0.f, 0.f, 0.f, 0.f};
    int i = 0;
    for (; me - i >= 32; i += 32) agg_chunk<4, false>(t4, rec, beg, wave, me, i, g, gl, s);
    int rem = me - i;  // wave-uniform, 0..31
    if (rem > 24)      agg_chunk<4, true>(t4, rec, beg, wave, me, i, g, gl, s);
    else if (rem > 16) agg_chunk<3, true>(t4, rec, beg, wave, me, i, g, gl, s);
    else if (rem > 8)  agg_chunk<2, true>(t4, rec, beg, wave, me, i, g, gl, s);
    else if (rem > 0)  agg_chunk<1, true>(t4, rec, beg, wave, me, i, g, gl, s);
#pragma unroll
    for (int k = 0; k < 8; k++) {
        s[k] += __shfl_xor(s[k], 8);
        s[k] += __shfl_xor(s[k], 16);
        s[k] += __shfl_xor(s[k], 32);
    }
    if (g == 0) {  // lanes 0..7: lane gl holds channels [8gl, 8gl+8)
        agg_consume(selfv, 1.f, s);  // + self row
        float d = dinv[wave];
        const float4* b4 = (const float4*)bias;
        float4 bb0 = b4[gl * 2], bb1 = b4[gl * 2 + 1];
        float o0 = fmaxf(fmaf(s[0], d, bb0.x), 0.f);
        float o1 = fmaxf(fmaf(s[1], d, bb0.y), 0.f);
        float o2 = fmaxf(fmaf(s[2], d, bb0.z), 0.f);
        float o3 = fmaxf(fmaf(s[3], d, bb0.w), 0.f);
        float o4 = fmaxf(fmaf(s[4], d, bb1.x), 0.f);
        float o5 = fmaxf(fmaf(s[5], d, bb1.y), 0.f);
        float o6 = fmaxf(fmaf(s[6], d, bb1.z), 0.f);
        float o7 = fmaxf(fmaf(s[7], d, bb1.w), 0.f);
        __half2 p0 = __floats2half2_rn(o0, o1);
        __half2 p1 = __floats2half2_rn(o2, o3);
        __half2 p2 = __floats2half2_rn(o4, o5);
        __half2 p3 = __floats2half2_rn(o6, o7);
        ((uint4*)acc)[(size_t)wave * 8 + gl] =
            make_uint4(*(unsigned int*)&p0, *(unsigned int*)&p1,
                       *(unsigned int*)&p2, *(unsigned int*)&p3);
    }
}

// ----- gemm64 tile: out = f16((in @ Wh) * dinv), 64 rows ------------------
__device__ __forceinline__ void dev_gemm64(int bb, int* smem,
                                           const unsigned short* __restrict__ in,
                                           const unsigned short* __restrict__ Wh,
                                           unsigned short* __restrict__ out,
                                           const float* __restrict__ dinv, int n) {
    uint4* sA = (uint4*)smem;  // 64 rows x 64 f16 = 8 KB
    int tid = threadIdx.x;
    int lane = tid & 63, wave = tid >> 6;
    unsigned int wu[32];
    {
        const uint4* col = (const uint4*)(Wh + (size_t)lane * 64);
#pragma unroll
        for (int j = 0; j < 8; j++) {
            uint4 w4 = col[j];
            wu[4 * j] = w4.x; wu[4 * j + 1] = w4.y;
            wu[4 * j + 2] = w4.z; wu[4 * j + 3] = w4.w;
        }
    }
    int base = bb * 64;
    const uint2* A2 = (const uint2*)in;
    int lim = n * 16;
    for (int i = tid; i < 1024; i += 256) {
        int gi = base * 16 + i;
        ((uint2*)sA)[i] = (gi < lim) ? A2[gi] : make_uint2(0u, 0u);
    }
    __syncthreads();
    int r0 = base + wave * 16;
    int r1 = min(r0 + 16, n);
    for (int r = r0; r < r1; r++) {
        int rr = r - base;
        float a0 = 0.f, a1 = 0.f;
#pragma unroll
        for (int j = 0; j < 8; j++) {
            uint4 u = sA[rr * 8 + j];  // uniform addr -> LDS broadcast, b128
            a0 = dot2(u.x, wu[4 * j], a0);
            a1 = dot2(u.y, wu[4 * j + 1], a1);
            a0 = dot2(u.z, wu[4 * j + 2], a0);
            a1 = dot2(u.w, wu[4 * j + 3], a1);
        }
        __half hv = __float2half_rn((a0 + a1) * dinv[r]);
        out[(size_t)r * 64 + lane] = *(unsigned short*)&hv;
    }
    __syncthreads();  // LDS reuse guard
}

// ----- gemm32 tile: out[r,0:32] = in @ Whl + blin (fp32), 64 rows ---------
__device__ __forceinline__ void dev_gemm32(int bb, int* smem,
                                           const unsigned short* __restrict__ in,
                                           const unsigned short* __restrict__ Wh,
                                           const float* __restrict__ b,
                                           float* __restrict__ out, int n) {
    uint4* sA = (uint4*)smem;
    int tid = threadIdx.x;
    int lane = tid & 63, wave = tid >> 6;
    int c = lane & 31;
    unsigned int wu[32];
    {
        const uint4* col = (const uint4*)(Wh + (size_t)c * 64);
#pragma unroll
        for (int j = 0; j < 8; j++) {
            uint4 w4 = col[j];
            wu[4 * j] = w4.x; wu[4 * j + 1] = w4.y;
            wu[4 * j + 2] = w4.z; wu[4 * j + 3] = w4.w;
        }
    }
    float bl = b[c];
    int base = bb * 64;
    const uint2* A2 = (const uint2*)in;
    int lim = n * 16;
    for (int i = tid; i < 1024; i += 256) {
        int gi = base * 16 + i;
        ((uint2*)sA)[i] = (gi < lim) ? A2[gi] : make_uint2(0u, 0u);
    }
    __syncthreads();
    int r0 = base + wave * 16;
    int r1 = min(r0 + 16, n);
    for (int r = r0; r < r1; r++) {
        int rr = r - base;
        float a0 = 0.f, a1 = 0.f;
#pragma unroll
        for (int j = 0; j < 8; j++) {
            uint4 u = sA[rr * 8 + j];
            a0 = dot2(u.x, wu[4 * j], a0);
            a1 = dot2(u.y, wu[4 * j + 1], a1);
            a0 = dot2(u.z, wu[4 * j + 2], a0);
            a1 = dot2(u.w, wu[4 * j + 3], a1);
        }
        if (lane < 32) out[(size_t)r * 32 + c] = bl + a0 + a1;
    }
    __syncthreads();  // LDS reuse guard
}

// ===========================================================================
// pipeline: the entire post-memset computation in ONE cooperative launch.
// 5 grid syncs replace 5 launch boundaries (~10 us each on this harness).
// acc aliases t32 (t32's last read is in P2's convert).
// ===========================================================================
__global__ __launch_bounds__(256) void pipeline(
        const void* ei, int E, int* bcur, int NB, int* staging,
        int NEB, int GB,
        const float* x, const float* W1, float* t32,
        const float* W2, const float* Wlin,
        unsigned short* Wh2, unsigned short* Whl,
        int* offs, float* dinv, int* rec, unsigned short* t16,
        const float* b1, const float* b2, const float* blin,
        float* out, int N) {
    __shared__ __align__(16) int smem[5128];
    cg::grid_group grid = cg::this_grid();
    unsigned short* acc = (unsigned short*)t32;
    // P1: bin (NEB) || gemm1 (GB) || W-convert (1), grid-strided
    int NW1 = NEB + GB + 1;
    for (int wi = blockIdx.x; wi < NW1; wi += gridDim.x) {
        if (wi < NEB)          dev_bin(wi, smem, ei, E, bcur, NB, staging);
        else if (wi < NEB + GB) dev_gemm1(wi - NEB, smem, x, W1, t32, N);
        else                    dev_wconv(W2, Wlin, Wh2, Whl);
    }
    grid.sync();
    // P2: per-bucket placement + scale/convert
    for (int wi = blockIdx.x; wi < NB; wi += gridDim.x)
        dev_place(wi, smem, staging, bcur, offs, dinv, rec, t32, t16, N, NB);
    grid.sync();
    int NQ = (N + 3) >> 2;
    // P3: aggregate layer 1 (t16 -> acc)
    for (int wi = blockIdx.x; wi < NQ; wi += gridDim.x)
        dev_agg(wi, t16, offs, rec, dinv, b1, acc, N);
    grid.sync();
    // P4: gemm64 (acc -> t16, scaled by dinv)
    for (int wi = blockIdx.x; wi < GB; wi += gridDim.x)
        dev_gemm64(wi, smem, acc, Wh2, t16, dinv, N);
    grid.sync();
    // P5: aggregate layer 2 (t16 -> acc)
    for (int wi = blockIdx.x; wi < NQ; wi += gridDim.x)
        dev_agg(wi, t16, offs, rec, dinv, b2, acc, N);
    grid.sync();
    // P6: gemm32 (acc -> out)
    for (int wi = blockIdx.x; wi < GB; wi += gridDim.x)
        dev_gemm32(wi, smem, acc, Whl, blin, out, N);
}

// ===========================================================================
// Fallback wrappers (non-cooperative path; identical logic).
// ===========================================================================
__global__ __launch_bounds__(256) void k_fat(const void* ei, int E, int* bcur, int NB,
                                             int* staging, int NEB, int GB,
                                             const float* x, const float* W1,
                                             float* t32, int n,
                                             const float* W2, const float* Wlin,
                                             unsigned short* Wh2, unsigned short* Whl) {
    __shared__ __align__(16) int smem[5128];
    int b = blockIdx.x;
    if (b < NEB) dev_bin(b, smem, ei, E, bcur, NB, staging);
    else if (b < NEB + GB) dev_gemm1(b - NEB, smem, x, W1, t32, n);
    else dev_wconv(W2, Wlin, Wh2, Whl);
}

__global__ __launch_bounds__(256) void k_place(const int* staging, const int* bcur,
                                               int* offs, float* dinv, int* rec,
                                               const float* t32, unsigned short* t16,
                                               int N, int NB) {
    __shared__ __align__(16) int smem[2048];
    dev_place(blockIdx.x, smem, staging, bcur, offs, dinv, rec, t32, t16, N, NB);
}

__global__ void k_agg(const unsigned short* t, const int* offs, const int* rec,
                      const float* dinv, const float* bias,
                      unsigned short* acc, int n) {
    dev_agg(blockIdx.x, t, offs, rec, dinv, bias, acc, n);
}

__global__ __launch_bounds__(256) void k_gemm64(const unsigned short* in,
                                                const unsigned short* Wh,
                                                unsigned short* out,
                                                const float* dinv, int n) {
    __shared__ __align__(16) int smem[2048];
    dev_gemm64(blockIdx.x, smem, in, Wh, out, dinv, n);
}

__global__ __launch_bounds__(256) void k_gemm32(const unsigned short* in,
                                                const unsigned short* Wh,
                                                const float* b, float* out, int n) {
    __shared__ __align__(16) int smem[2048];
    dev_gemm32(blockIdx.x, smem, in, Wh, b, out, n);
}

extern "C" void kernel_launch(void* const* d_in, const int* in_sizes, int n_in,
                              void* d_out, int out_size, void* d_ws, size_t ws_size,
                              hipStream_t stream) {
    (void)n_in; (void)out_size; (void)ws_size;
    const float* x    = (const float*)d_in[0];
    const void*  ei   = d_in[1];
    const float* W1   = (const float*)d_in[2];
    const float* b1   = (const float*)d_in[3];
    const float* W2   = (const float*)d_in[4];
    const float* b2   = (const float*)d_in[5];
    const float* Wlin = (const float*)d_in[6];
    const float* blin = (const float*)d_in[7];
    float* out = (float*)d_out;

    const int N = in_sizes[0] / IN_C;
    const int E = in_sizes[1] / 2;
    const int NB = (N + S_NODES - 1) / S_NODES;    // buckets (196)
    const int NEB = (E + CHUNK_E - 1) / CHUNK_E;   // bin work items (391)
    const int GB = (N + 63) / 64;                  // 64-row gemm tiles (1563)

    char* ws = (char*)d_ws;
    size_t off = 0;
    auto alloc = [&](size_t bytes) -> void* {
        size_t a = (off + 255) & ~(size_t)255;
        off = a + bytes;
        return (void*)(ws + a);
    };
    int*   offs    = (int*)  alloc((size_t)(N + 1) * 4);
    float* dinv    = (float*)alloc((size_t)N * 4);
    int*   bcur    = (int*)  alloc((size_t)NB * 4);
    int*   rec     = (int*)  alloc((size_t)E * 4);
    int*   staging = (int*)  alloc((size_t)NB * S_CAP * 4);  // follows rec: OOB slack
    float* t32     = (float*)alloc((size_t)N * HID_C * 4);   // fp32 unscaled gemm1
    unsigned short* t16 = (unsigned short*)alloc((size_t)N * HID_C * 2);
    unsigned short* Wh2 = (unsigned short*)alloc(64 * 64 * 2);
    unsigned short* Whl = (unsigned short*)alloc(64 * 32 * 2);
    unsigned short* acc = (unsigned short*)t32;  // alias (see pipeline comment)

    hipMemsetAsync(bcur, 0, (size_t)NB * 4, stream);

    // One-time (cached) cooperative-capability + occupancy probe. Host-side
    // queries only -- graph-capture safe.
    static int g_coop = -1;
    static int g_grid = 0;
    if (g_coop < 0) {
        int dev = 0;
        hipGetDevice(&dev);
        int coop = 0;
        hipDeviceGetAttribute(&coop, hipDeviceAttributeCooperativeLaunch, dev);
        int maxB = 0, ncu = 0;
        if (coop) {
            if (hipOccupancyMaxActiveBlocksPerMultiprocessor(&maxB, pipeline, 256, 0)
                    != hipSuccess || maxB < 1)
                coop = 0;
        }
        hipDeviceGetAttribute(&ncu, hipDeviceAttributeMultiprocessorCount, dev);
        if (ncu <= 0) ncu = 256;
        g_coop = coop;
        g_grid = maxB * ncu;
        if (g_grid <= 0) g_coop = 0;
    }

    if (g_coop) {
        void* args[] = {
            (void*)&ei, (void*)&E, (void*)&bcur, (void*)&NB, (void*)&staging,
            (void*)&NEB, (void*)&GB,
            (void*)&x, (void*)&W1, (void*)&t32,
            (void*)&W2, (void*)&Wlin, (void*)&Wh2, (void*)&Whl,
            (void*)&offs, (void*)&dinv, (void*)&rec, (void*)&t16,
            (void*)&b1, (void*)&b2, (void*)&blin,
            (void*)&out, (void*)&N};
        hipLaunchCooperativeKernel((void*)pipeline, dim3(g_grid), dim3(256),
                                   args, 0, stream);
    } else {
        // fallback: round-8 sequential chain
        k_fat<<<NEB + GB + 1, 256, 0, stream>>>(ei, E, bcur, NB, staging, NEB, GB,
                                                x, W1, t32, N, W2, Wlin, Wh2, Whl);
        k_place<<<NB, 256, 0, stream>>>(staging, bcur, offs, dinv, rec, t32, t16, N, NB);
        k_agg<<<(N + 3) / 4, 256, 0, stream>>>(t16, offs, rec, dinv, b1, acc, N);
        k_gemm64<<<GB, 256, 0, stream>>>(acc, Wh2, t16, dinv, N);
        k_agg<<<(N + 3) / 4, 256, 0, stream>>>(t16, offs, rec, dinv, b2, acc, N);
        k_gemm32<<<GB, 256, 0, stream>>>(acc, Whl, blin, out, N);
    }
}

// Round 10
// 243.252 us; speedup vs baseline: 3.1918x; 3.1918x over previous
//
#include <hip/hip_runtime.h>
#include <hip/hip_fp16.h>

#define IN_C 64
#define HID_C 64
#define OUT_C 32
#define S_NODES  512    // bucket width in nodes
#define S_CAP  12288    // staging capacity per bucket (mean 8192, sigma ~90)
#define CHUNK_E 4096    // edges per bin block (16 per thread, register-cached)
// Packing invariant: src fits in 17 bits (N <= 131072), dst-local in 9 bits.

typedef _Float16 f16_t;
typedef f16_t f16x2 __attribute__((ext_vector_type(2)));

// 2 f16 MACs, fp32 accumulate (v_dot2_f32_f16). Both operands as packed u32.
__device__ __forceinline__ float dot2(unsigned int a, unsigned int b, float c) {
#if __has_builtin(__builtin_amdgcn_fdot2)
    return __builtin_amdgcn_fdot2(*(f16x2*)&a, *(f16x2*)&b, c, false);
#else
    float2 af = __half22float2(*(__half2*)&a);
    float2 bf = __half22float2(*(__half2*)&b);
    return fmaf(af.x, bf.x, fmaf(af.y, bf.y, c));
#endif
}

// s0 += f16lo(p)*w ; s1 += f16hi(p)*w  -- v_fma_mix_f32 does the f16->f32
// convert inside the FMA (bit-exact with cvt+fmaf, half the instructions).
__device__ __forceinline__ void mix2(float& s0, float& s1, unsigned int p, float w) {
    asm("v_fma_mix_f32 %0, %2, %3, %0 op_sel:[0,0,0] op_sel_hi:[1,0,0]\n\t"
        "v_fma_mix_f32 %1, %2, %3, %1 op_sel:[1,0,0] op_sel_hi:[1,0,0]"
        : "+v"(s0), "+v"(s1)
        : "v"(p), "v"(w));
}

// Wave-level inclusive scan (64 lanes) via shfl_up; 6 steps, no barriers.
__device__ __forceinline__ int wave_iscan(int x, int lane) {
#pragma unroll
    for (int o = 1; o < 64; o <<= 1) {
        int y = __shfl_up(x, o);
        if (lane >= o) x += y;
    }
    return x;
}

// ---------------------------------------------------------------------------
// fat: three independent jobs in one launch (overlap without streams, which
// graph capture forbids):
//   blocks [0, NEB)        : bin_edges -- single-pass edge read into VGPR
//                            cache (16 records/thread, dword loads only),
//                            LDS histogram + wave-shfl scan, LDS counting-
//                            sort, burst-copy segments into bucket staging.
//                            is64 detected inline per block.
//   blocks [NEB, NEB+GB)   : gemm1: t32[r,:] = x[r,:] @ W1 in FP32, UNSCALED
//                            (dinv doesn't exist yet; place_fine applies it
//                            during its coalesced f16 conversion pass --
//                            bit-exact with the single-rounding path).
//   block  NEB+GB          : W2/Wlin -> f16 col-major for later kernels.
// NOTE (round-9 lesson): do NOT fuse these phases with grid.sync() into one
// cooperative kernel -- the monolith carries worst-case VGPR/LDS for all
// phases (112 VGPR / 21 KB), occupancy collapses to 24%, and the latency-
// bound gather phases lose their TLP (measured 600 us vs ~150 us split).
// ---------------------------------------------------------------------------
__global__ __launch_bounds__(256) void fat(const void* ei, int E,
                                           int* bcur, int NB,
                                           int* __restrict__ staging,
                                           int NEB, int GB,
                                           const float* __restrict__ x,
                                           const float* __restrict__ W1,
                                           float* __restrict__ t32, int n,
                                           const float* __restrict__ W2,
                                           const float* __restrict__ Wlin,
                                           unsigned short* __restrict__ Wh2,
                                           unsigned short* __restrict__ Whl) {
    // union: bin = cnt(256)+boff(256)+lcur(256)+gbase(256)+stg(4096)+misc
    //        gemm = sA (4 KB)
    __shared__ __align__(16) int smem[5128];
    int tid = threadIdx.x;
    int b = blockIdx.x;
    if (b < NEB) {
        // ----- bin_edges -----
        int* cnt = smem;          int* boff = smem + 256;
        int* lcur = smem + 512;   int* gbase = smem + 768;
        int* stg = smem + 1024;   // CHUNK_E ints
        int* ps64 = smem + 5120;
        int* wsum = smem + 5121;  // 4 wave partial sums
        int lane = tid & 63, wv = tid >> 6;
        if (tid == 0) *ps64 = 1;
        cnt[tid] = 0;
        __syncthreads();
        // int32 interp: odd ints are real node ids (nonzero w.h.p.);
        // int64 interp: odd ints are high dwords (always 0 for ids < 2^31).
        if (2 * tid + 1 < 2 * E && ((const int*)ei)[2 * tid + 1] != 0) *ps64 = 0;
        __syncthreads();
        int is64 = *ps64;
        int e0 = b * CHUNK_E;
        int e1 = min(E, e0 + CHUNK_E);
        const int* ei32 = (const int*)ei;
        int rbuf[16];   // packed record  src | ((dst&511)<<17)
        int bbuf[16];   // bucket id (dst>>9), -1 = invalid slot
        if (is64) {
#pragma unroll
            for (int k = 0; k < 16; k++) {
                int e = e0 + (k << 8) + tid;
                if (e < e1) {
                    int src = ei32[2 * e];            // low dword of int64
                    int dst = ei32[2 * (E + e)];
                    rbuf[k] = src | ((dst & 511) << 17);
                    int bk = dst >> 9;
                    bbuf[k] = bk;
                    atomicAdd(&cnt[bk], 1);
                } else bbuf[k] = -1;
            }
        } else {
#pragma unroll
            for (int k = 0; k < 16; k++) {
                int e = e0 + (k << 8) + tid;
                if (e < e1) {
                    int src = ei32[e];
                    int dst = ei32[E + e];
                    rbuf[k] = src | ((dst & 511) << 17);
                    int bk = dst >> 9;
                    bbuf[k] = bk;
                    atomicAdd(&cnt[bk], 1);
                } else bbuf[k] = -1;
            }
        }
        __syncthreads();
        // exclusive scan of cnt via wave-shfl (2 barriers)
        int v = cnt[tid];
        int xx = wave_iscan(v, lane);
        if (lane == 63) wsum[wv] = xx;
        __syncthreads();
        int add = 0;
#pragma unroll
        for (int w = 0; w < 3; w++) add += (w < wv) ? wsum[w] : 0;
        int bo = xx + add - v;
        boff[tid] = bo;
        lcur[tid] = bo;
        __syncthreads();
        // counting-sort scatter from registers
#pragma unroll
        for (int k = 0; k < 16; k++) {
            if (bbuf[k] >= 0) {
                int p = atomicAdd(&lcur[bbuf[k]], 1);
                stg[p] = rbuf[k];
            }
        }
        __syncthreads();
        if (tid < NB && cnt[tid] > 0) gbase[tid] = atomicAdd(&bcur[tid], cnt[tid]);
        __syncthreads();
        int sw = tid >> 4, sl = tid & 15;  // 16 subwaves of 16 lanes
        for (int bk = sw; bk < NB; bk += 16) {
            int c = cnt[bk];
            if (c == 0) continue;
            int o = boff[bk], g = gbase[bk];
            size_t gb = (size_t)bk * S_CAP;
            for (int j = sl; j < c; j += 16) {
                if (g + j < S_CAP) staging[gb + g + j] = stg[o + j];  // clamp (never hits)
            }
        }
    } else if (b < NEB + GB) {
        // ----- gemm1: fp32 unscaled x @ W1 (scaled+f16'd by place_fine) -----
        uint4* sA = (uint4*)smem;  // 32 rows x 64 f16 = 4 KB
        int bb = b - NEB;
        int lane = tid & 63, wave = tid >> 6;
        unsigned int wu[32];
#pragma unroll
        for (int k = 0; k < 32; k++) {
            f16x2 p;
            p.x = (f16_t)W1[(2 * k) * 64 + lane];
            p.y = (f16_t)W1[(2 * k + 1) * 64 + lane];
            wu[k] = *(unsigned int*)&p;
        }
        int base = bb * 32;
        const float2* A2 = (const float2*)x;
        int lim = n * 32;
        for (int i = tid; i < 1024; i += 256) {
            int gi = base * 32 + i;
            float2 v = (gi < lim) ? A2[gi] : make_float2(0.f, 0.f);
            ((__half2*)sA)[i] = __floats2half2_rn(v.x, v.y);
        }
        __syncthreads();
        int r0 = base + wave * 8;
        int r1 = min(r0 + 8, n);
        for (int r = r0; r < r1; r++) {
            int rr = r - base;
            float a0 = 0.f, a1 = 0.f;
#pragma unroll
            for (int j = 0; j < 8; j++) {
                uint4 u = sA[rr * 8 + j];  // uniform addr -> LDS broadcast, b128
                a0 = dot2(u.x, wu[4 * j], a0);
                a1 = dot2(u.y, wu[4 * j + 1], a1);
                a0 = dot2(u.z, wu[4 * j + 2], a0);
                a1 = dot2(u.w, wu[4 * j + 3], a1);
            }
            t32[(size_t)r * 64 + lane] = a0 + a1;
        }
    } else {
        // ----- W2 / Wlin -> f16 col-major -----
        for (int i = tid; i < 4096; i += 256) {
            int r = i >> 6, c = i & 63;
            f16_t h2 = (f16_t)W2[r * 64 + c];
            Wh2[c * 64 + r] = *(unsigned short*)&h2;
        }
        for (int i = tid; i < 2048; i += 256) {
            int r = i >> 5, c = i & 31;
            f16_t h = (f16_t)Wlin[r * 32 + c];
            Whl[c * 64 + r] = *(unsigned short*)&h;
        }
    }
}

// ---------------------------------------------------------------------------
// Pass B: one block per bucket, 1024 THREADS (16 waves: 196 blocks land ~1
// per CU, so block width is the only occupancy lever -- 4x the MLP of the
// 256-thread version). Wave-shfl scans; LDS degree histogram of the staged
// records -> offs/dinv/cursors; scatter of src records into the bucket's
// contiguous rec region; then the coalesced scale+convert pass
// t16[r,:] = f16(t32[r,:]*dinv[r]) (bit-exact single rounding).
// ---------------------------------------------------------------------------
__global__ __launch_bounds__(1024) void place_fine(const int* __restrict__ staging,
                                                   const int* __restrict__ bcur,
                                                   int* __restrict__ offs,
                                                   float* __restrict__ dinv,
                                                   int* __restrict__ rec,
                                                   const float* __restrict__ t32,
                                                   unsigned short* __restrict__ t16,
                                                   int N, int NB) {
    __shared__ int sdeg[S_NODES];
    __shared__ int curs[S_NODES];
    __shared__ int sb[256];
    __shared__ float sdinv[S_NODES];
    __shared__ int wsum[16];
    int tid = threadIdx.x;
    int lane = tid & 63, wv = tid >> 6;
    if (tid < S_NODES) sdeg[tid] = 0;
    // scan A (first 4 waves): bucket counts -> sb (inclusive)
    if (tid < 256) {
        int v = (tid < NB) ? min(bcur[tid], S_CAP) : 0;
        int xx = wave_iscan(v, lane);
        if (lane == 63) wsum[wv] = xx;
        sb[tid] = xx;  // partial; fixed after barrier
    }
    __syncthreads();
    if (tid < 256) {
        int add = 0;
#pragma unroll
        for (int w = 0; w < 3; w++) add += (w < wv) ? wsum[w] : 0;
        sb[tid] += add;
    }
    __syncthreads();
    int cnt = min(bcur[blockIdx.x], S_CAP);
    int bbase = sb[blockIdx.x] - cnt;  // exclusive prefix for this bucket
    if (blockIdx.x == NB - 1 && tid == 0) offs[N] = sb[255];
    int base = blockIdx.x * S_NODES;
    int nn = min(S_NODES, N - base);
    size_t sbase = (size_t)blockIdx.x * S_CAP;
    for (int j = tid; j < cnt; j += 1024) atomicAdd(&sdeg[staging[sbase + j] >> 17], 1);
    __syncthreads();
    // scan B (first 8 waves, 1 degree/thread): degrees -> exclusive prefix
    int d = (tid < S_NODES) ? sdeg[tid] : 0;
    int x2 = wave_iscan(d, lane);
    if (tid < S_NODES && lane == 63) wsum[wv] = x2;
    __syncthreads();
    if (tid < S_NODES) {
        int add2 = 0;
#pragma unroll
        for (int w = 0; w < 7; w++) add2 += (w < wv) ? wsum[w] : 0;
        int pre = bbase + x2 + add2 - d;  // exclusive
        curs[tid] = pre;
        float dv = rsqrtf((float)(d + 1));
        sdinv[tid] = dv;
        if (tid < nn) {
            offs[base + tid] = pre;
            dinv[base + tid] = dv;
        }
    }
    __syncthreads();
    for (int j = tid; j < cnt; j += 1024) {
        int pk = staging[sbase + j];
        int p = atomicAdd(&curs[pk >> 17], 1);
        rec[p] = pk & 0x1FFFF;
    }
    // ----- scale+convert this bucket's rows: t16[r,:] = f16(t32[r,:]*dinv[r])
    const float4* tin = (const float4*)t32 + (size_t)base * 16;  // 16 float4/row
    uint2* tout = (uint2*)t16 + (size_t)base * 16;               // 16 uint2/row
    int jmax = nn * 16;
    for (int j = tid; j < jmax; j += 1024) {
        float4 vv = tin[j];
        float w = sdinv[j >> 4];
        __half2 h0 = __floats2half2_rn(vv.x * w, vv.y * w);
        __half2 h1 = __floats2half2_rn(vv.z * w, vv.w * w);
        tout[j] = make_uint2(*(unsigned int*)&h0, *(unsigned int*)&h1);
    }
}

// ---------------------------------------------------------------------------
// aggregate helpers: chunk<NU> issues NU batched row loads (unconditional
// within the chunk -> full MLP, round-2 lesson) then NU masked consumes via
// v_fma_mix_f32 (f16->f32 convert fused into the FMA: 8 VALU per uint4
// instead of 16; the 0/1 mask rides in the multiplicand for free).
// NU is selected by wave-uniform m -> pure s_cbranch, no divergence.
// ---------------------------------------------------------------------------
__device__ __forceinline__ void agg_consume(const uint4& v, float w, float s[8]) {
    mix2(s[0], s[1], v.x, w);
    mix2(s[2], s[3], v.y, w);
    mix2(s[4], s[5], v.z, w);
    mix2(s[6], s[7], v.w, w);
}

template <int NU>
__device__ __forceinline__ void agg_chunk(const uint4* __restrict__ t4,
                                          const int* __restrict__ rec,
                                          int beg, int node, int m, int i,
                                          int g, int gl, float s[8]) {
    int srcs[NU];
    float ws[NU];
    uint4 vs[NU];
#pragma unroll
    for (int u = 0; u < NU; u++) {
        int it = i + u * 8 + g;
        srcs[u] = (it == 0) ? node : ((it < m) ? rec[beg + it - 1] : node);
        ws[u] = (it < m) ? 1.f : 0.f;
    }
#pragma unroll
    for (int u = 0; u < NU; u++) vs[u] = t4[(size_t)srcs[u] * 8 + gl];
#pragma unroll
    for (int u = 0; u < NU; u++) agg_consume(vs[u], ws[u], s);
}

// ---------------------------------------------------------------------------
// acc[n,:] = f16( relu( b + dinv[n] * ( t[n,:] + sum_{edges->n} t[src,:] )))
// t rows pre-scaled by dinv[src] (place_fine for layer 1, gemm64 for layer
// 2). One wave per node: 8 groups x 8 lanes; each group fetches one item's
// 128B row as uint4. fp32 accum.
// ---------------------------------------------------------------------------
__global__ void aggregate(const unsigned short* __restrict__ t,
                          const int* __restrict__ offs, const int* __restrict__ rec,
                          const float* __restrict__ dinv, const float* __restrict__ bias,
                          unsigned short* __restrict__ acc, int n) {
    int wave = (blockIdx.x * blockDim.x + threadIdx.x) >> 6;
    int lane = threadIdx.x & 63;
    if (wave >= n) return;
    int g = lane >> 3;   // item group 0..7
    int gl = lane & 7;   // 16B slot within the 128B row
    int beg = offs[wave], end = offs[wave + 1];
    int m = end - beg + 1;  // item 0 = self row
    const uint4* t4 = (const uint4*)t;
    float s[8] = {0.f, 0.f, 0.f, 0.f, 0.f, 0.f, 0.f, 0.f};
    int i = 0;
    for (; m - i > 24; i += 32) agg_chunk<4>(t4, rec, beg, wave, m, i, g, gl, s);
    int rem = m - i;  // wave-uniform
    if (rem > 16)     agg_chunk<3>(t4, rec, beg, wave, m, i, g, gl, s);
    else if (rem > 8) agg_chunk<2>(t4, rec, beg, wave, m, i, g, gl, s);
    else if (rem > 0) agg_chunk<1>(t4, rec, beg, wave, m, i, g, gl, s);
#pragma unroll
    for (int k = 0; k < 8; k++) {
        s[k] += __shfl_xor(s[k], 8);
        s[k] += __shfl_xor(s[k], 16);
        s[k] += __shfl_xor(s[k], 32);
    }
    if (g == 0) {  // lanes 0..7: lane gl holds channels [8gl, 8gl+8)
        float d = dinv[wave];
        const float4* b4 = (const float4*)bias;
        float4 bb0 = b4[gl * 2], bb1 = b4[gl * 2 + 1];
        float o0 = fmaxf(fmaf(s[0], d, bb0.x), 0.f);
        float o1 = fmaxf(fmaf(s[1], d, bb0.y), 0.f);
        float o2 = fmaxf(fmaf(s[2], d, bb0.z), 0.f);
        float o3 = fmaxf(fmaf(s[3], d, bb0.w), 0.f);
        float o4 = fmaxf(fmaf(s[4], d, bb1.x), 0.f);
        float o5 = fmaxf(fmaf(s[5], d, bb1.y), 0.f);
        float o6 = fmaxf(fmaf(s[6], d, bb1.z), 0.f);
        float o7 = fmaxf(fmaf(s[7], d, bb1.w), 0.f);
        __half2 p0 = __floats2half2_rn(o0, o1);
        __half2 p1 = __floats2half2_rn(o2, o3);
        __half2 p2 = __floats2half2_rn(o4, o5);
        __half2 p3 = __floats2half2_rn(o6, o7);
        ((uint4*)acc)[(size_t)wave * 8 + gl] =
            make_uint4(*(unsigned int*)&p0, *(unsigned int*)&p1,
                       *(unsigned int*)&p2, *(unsigned int*)&p3);
    }
}

// ---------------------------------------------------------------------------
// gemm64: out[r,c] = f16( (in[r,:] @ W)[c] * dinv[r] ), f16 input, W pre-
// converted f16 col-major (8x b128 column load, no cvt). A staged in LDS;
// uniform ds_read_b128 broadcast. 32 dot2/row per lane, 8 rows per wave.
// ---------------------------------------------------------------------------
__global__ __launch_bounds__(256) void gemm64(const unsigned short* __restrict__ in,
                                              const unsigned short* __restrict__ Wh,
                                              unsigned short* __restrict__ out,
                                              const float* __restrict__ dinv, int n) {
    __shared__ uint4 sA[32 * 8];  // 32 rows x 64 f16 = 4 KB
    int tid = threadIdx.x;
    int lane = tid & 63, wave = tid >> 6;
    unsigned int wu[32];
    {
        const uint4* col = (const uint4*)(Wh + (size_t)lane * 64);
#pragma unroll
        for (int j = 0; j < 8; j++) {
            uint4 w4 = col[j];
            wu[4 * j] = w4.x; wu[4 * j + 1] = w4.y;
            wu[4 * j + 2] = w4.z; wu[4 * j + 3] = w4.w;
        }
    }
    int base = blockIdx.x * 32;
    const uint2* A2 = (const uint2*)in;
    int lim = n * 16;
    for (int i = tid; i < 512; i += 256) {
        int gi = base * 16 + i;
        ((uint2*)sA)[i] = (gi < lim) ? A2[gi] : make_uint2(0u, 0u);
    }
    __syncthreads();
    int r0 = base + wave * 8;
    int r1 = min(r0 + 8, n);
    for (int r = r0; r < r1; r++) {
        int rr = r - base;
        float a0 = 0.f, a1 = 0.f;
#pragma unroll
        for (int j = 0; j < 8; j++) {
            uint4 u = sA[rr * 8 + j];  // uniform addr -> LDS broadcast, b128
            a0 = dot2(u.x, wu[4 * j], a0);
            a1 = dot2(u.y, wu[4 * j + 1], a1);
            a0 = dot2(u.z, wu[4 * j + 2], a0);
            a1 = dot2(u.w, wu[4 * j + 3], a1);
        }
        __half hv = __float2half_rn((a0 + a1) * dinv[r]);
        out[(size_t)r * 64 + lane] = *(unsigned short*)&hv;
    }
}

// ---------------------------------------------------------------------------
// gemm32: out[r,0:32] = in[r,0:64] @ Wlin + blin (fp32 out). Wlin pre-
// converted f16 col-major. Lanes 32..63 compute duplicate columns, only
// lane<32 stores. Input (acc) is f16, already relu'd by aggregate.
// ---------------------------------------------------------------------------
__global__ __launch_bounds__(256) void gemm32(const unsigned short* __restrict__ in,
                                              const unsigned short* __restrict__ Wh,
                                              const float* __restrict__ b,
                                              float* __restrict__ out, int n) {
    __shared__ uint4 sA[32 * 8];
    int tid = threadIdx.x;
    int lane = tid & 63, wave = tid >> 6;
    int c = lane & 31;
    unsigned int wu[32];
    {
        const uint4* col = (const uint4*)(Wh + (size_t)c * 64);
#pragma unroll
        for (int j = 0; j < 8; j++) {
            uint4 w4 = col[j];
            wu[4 * j] = w4.x; wu[4 * j + 1] = w4.y;
            wu[4 * j + 2] = w4.z; wu[4 * j + 3] = w4.w;
        }
    }
    float bl = b[c];
    int base = blockIdx.x * 32;
    const uint2* A2 = (const uint2*)in;
    int lim = n * 16;
    for (int i = tid; i < 512; i += 256) {
        int gi = base * 16 + i;
        ((uint2*)sA)[i] = (gi < lim) ? A2[gi] : make_uint2(0u, 0u);
    }
    __syncthreads();
    int r0 = base + wave * 8;
    int r1 = min(r0 + 8, n);
    for (int r = r0; r < r1; r++) {
        int rr = r - base;
        float a0 = 0.f, a1 = 0.f;
#pragma unroll
        for (int j = 0; j < 8; j++) {
            uint4 u = sA[rr * 8 + j];
            a0 = dot2(u.x, wu[4 * j], a0);
            a1 = dot2(u.y, wu[4 * j + 1], a1);
            a0 = dot2(u.z, wu[4 * j + 2], a0);
            a1 = dot2(u.w, wu[4 * j + 3], a1);
        }
        if (lane < 32) out[(size_t)r * 32 + c] = bl + a0 + a1;
    }
}

extern "C" void kernel_launch(void* const* d_in, const int* in_sizes, int n_in,
                              void* d_out, int out_size, void* d_ws, size_t ws_size,
                              hipStream_t stream) {
    (void)n_in; (void)out_size; (void)ws_size;
    const float* x    = (const float*)d_in[0];
    const void*  ei   = d_in[1];
    const float* W1   = (const float*)d_in[2];
    const float* b1   = (const float*)d_in[3];
    const float* W2   = (const float*)d_in[4];
    const float* b2   = (const float*)d_in[5];
    const float* Wlin = (const float*)d_in[6];
    const float* blin = (const float*)d_in[7];
    float* out = (float*)d_out;

    const int N = in_sizes[0] / IN_C;
    const int E = in_sizes[1] / 2;
    const int NB = (N + S_NODES - 1) / S_NODES;    // buckets (196)
    const int NEB = (E + CHUNK_E - 1) / CHUNK_E;   // bin blocks (391)
    const int GB = (N + 31) / 32;                  // 32-row gemm blocks (3125)

    char* ws = (char*)d_ws;
    size_t off = 0;
    auto alloc = [&](size_t bytes) -> void* {
        size_t a = (off + 255) & ~(size_t)255;
        off = a + bytes;
        return (void*)(ws + a);
    };
    int*   offs    = (int*)  alloc((size_t)(N + 1) * 4);
    float* dinv    = (float*)alloc((size_t)N * 4);
    int*   bcur    = (int*)  alloc((size_t)NB * 4);
    int*   rec     = (int*)  alloc((size_t)E * 4);
    int*   staging = (int*)  alloc((size_t)NB * S_CAP * 4);  // follows rec: OOB slack
    float* t32     = (float*)alloc((size_t)N * HID_C * 4);  // fp32 unscaled gemm1
    unsigned short* t16 = (unsigned short*)alloc((size_t)N * HID_C * 2);
    unsigned short* Wh2 = (unsigned short*)alloc(64 * 64 * 2);
    unsigned short* Whl = (unsigned short*)alloc(64 * 32 * 2);
    // acc aliases t32: t32's last read is place_fine; acc first written after.
    unsigned short* acc = (unsigned short*)t32;

    hipMemsetAsync(bcur, 0, (size_t)NB * 4, stream);

    // bin_edges (391 blocks) || gemm1 (3125 blocks) || W-convert (1 block)
    fat<<<NEB + GB + 1, 256, 0, stream>>>(ei, E, bcur, NB, staging, NEB, GB,
                                          x, W1, t32, N, W2, Wlin, Wh2, Whl);
    place_fine<<<NB, 1024, 0, stream>>>(staging, bcur, offs, dinv, rec,
                                        t32, t16, N, NB);

    aggregate<<<(N + 3) / 4, 256, 0, stream>>>(t16, offs, rec, dinv, b1, acc, N);
    gemm64<<<GB, 256, 0, stream>>>(acc, Wh2, t16, dinv, N);
    aggregate<<<(N + 3) / 4, 256, 0, stream>>>(t16, offs, rec, dinv, b2, acc, N);
    gemm32<<<GB, 256, 0, stream>>>(acc, Whl, blin, out, N);
}